// Round 8
// baseline (1341.911 us; speedup 1.0000x reference)
//
#include <hip/hip_runtime.h>

// ============================================================================
// JumpODE (B=2048, T=128, H=64, N_STEPS=10) fused persistent kernel, gfx950.
// Round 8: R5 skeleton, 2-wave barrier groups, 1 block/CU.
//   256 blocks x 128 threads (2 waves, feature split 32/32), 8 real rows
//   (cols 8..15 mirror b&7). Differs from R6 ONLY in: 8 real rows + 256
//   blocks -> 1 block/CU (R6's regression came from 2 blocks/CU interference,
//   proven in R4). Symmetric waves (all compute integ/nll), static buffers,
//   biases in MFMA C-in, tim/msk staged (all proven-neutral-or-better).
//
// Fragment layouts (16x16x32 bf16, learn_hip verified):
//   A: row m = lane&15,  k = (lane>>4)*8 + e
//   B: col n = lane&15,  k = (lane>>4)*8 + e
//   C/D: col n = lane&15, row m = (lane>>4)*4 + reg
// ============================================================================

#define T_LEN 128

typedef float  f32x4  __attribute__((ext_vector_type(4)));
typedef __bf16 bf16x8 __attribute__((ext_vector_type(8)));
typedef __bf16 bf16x2 __attribute__((ext_vector_type(2)));

#define MFMA16(a, b, c) __builtin_amdgcn_mfma_f32_16x16x32_bf16((a), (b), (c), 0, 0, 0)

__device__ __forceinline__ float rcp_f(float x) { return __builtin_amdgcn_rcpf(x); }
__device__ __forceinline__ float exp2_f(float x) { return __builtin_amdgcn_exp2f(x); }
__device__ __forceinline__ float log2_f(float x) { return __builtin_amdgcn_logf(x); }

constexpr float kL2E = 1.44269504088896340736f;
constexpr float kLN2 = 0.69314718055994530942f;

__device__ __forceinline__ float tanh_fast(float x) {
  float e = exp2_f(x * (2.0f * kL2E));
  return 1.0f - 2.0f * rcp_f(e + 1.0f);
}
__device__ __forceinline__ float sigm_fast(float x) {
  return rcp_f(1.0f + exp2_f(-kL2E * x));
}
__device__ __forceinline__ float softplus_fast(float x) {
  float neg = log2_f(1.0f + exp2_f(-kL2E * fabsf(x))) * kLN2;
  return fmaxf(x, 0.0f) + neg;
}
__device__ __forceinline__ unsigned packbf(float a, float b) {
  bf16x2 v; v[0] = (__bf16)a; v[1] = (__bf16)b;   // RNE
  return __builtin_bit_cast(unsigned, v);
}

__launch_bounds__(128)
__global__ void jumpode_main(
    const float* __restrict__ times, const int* __restrict__ marks,
    const float* __restrict__ maskp, const float* __restrict__ W0,
    const float* __restrict__ b0,    const float* __restrict__ W1,
    const float* __restrict__ b1,    const float* __restrict__ W2,
    const float* __restrict__ b2,    const float* __restrict__ Wi,
    const float* __restrict__ bi,    const float* __restrict__ emb,
    const float* __restrict__ W_ih,  const float* __restrict__ W_hh,
    const float* __restrict__ b_ih,  const float* __restrict__ b_hh,
    float* __restrict__ out, float* __restrict__ ws)
{
  // ---- LDS (~62 KB) ----
  __shared__ __align__(16) unsigned whh_l[256 * 32];   // bf16 pairs, swizzled, 32 KB
  __shared__ __align__(16) float    gm1_l[8 * 256];    // m1@Wih^T + biases, swizzled, 8 KB
  __shared__ __align__(16) unsigned xb0[16 * 32];      // activation X^T bf16 buffers
  __shared__ __align__(16) unsigned xb1[16 * 32];
  __shared__ __align__(16) unsigned xb2[16 * 32];      // step-end / LSTM input
  __shared__ __align__(16) float    pint[3][16 * 2];   // intensity partials [b][wv]
  __shared__ __align__(16) float    b0_l[64], b1_l[64], b2_l[64];
  __shared__ __align__(16) float    w0c0_l[64];        // W0[:,0]
  __shared__ __align__(16) float    wihc0_l[256];      // W_ih[:,0]
  __shared__ __align__(16) float    emb16[8][64];
  __shared__ __align__(16) float    tim_l[8][T_LEN];
  __shared__ __align__(16) float    msk_l[8][T_LEN];

  const int tid = threadIdx.x;          // 0..127
  const int wv  = tid >> 6;             // wave id: features [32wv, 32wv+32)
  const int l   = tid & 63;
  const int b   = l & 15;               // MFMA batch column
  const int q   = l >> 4;               // lane quad
  const int bm  = b & 7;                // real batch row within block
  const int row = blockIdx.x * 8 + bm;  // global batch row (256*8 = 2048)
  const int xsw = b & 7;                // xor-swizzle key

  // ---- staging (128 threads) ----
  if (tid < 64) {
    b0_l[tid] = b0[tid]; b1_l[tid] = b1[tid]; b2_l[tid] = b2[tid];
    w0c0_l[tid] = W0[tid * 65];
  }
  for (int idx = tid; idx < 256; idx += 128) wihc0_l[idx] = W_ih[idx * 65];
  for (int idx = tid; idx < 512; idx += 128) {
    int rr = idx >> 6, cc = idx & 63;
    int mk = marks[(blockIdx.x * 8 + rr) * T_LEN + 1];
    emb16[rr][cc] = emb[mk * 64 + cc];
  }
  for (int idx = tid; idx < 1024; idx += 128) {
    int rr = idx >> 7, cc = idx & 127;
    tim_l[rr][cc] = times[(blockIdx.x * 8 + rr) * T_LEN + cc];
    msk_l[rr][cc] = maskp[(blockIdx.x * 8 + rr) * T_LEN + cc];
  }
  #pragma unroll 4
  for (int i = 0; i < 64; ++i) {                      // W_hh -> bf16 swizzled
    int idx = i * 128 + tid;                          // word: row*32 + c2
    int rw = idx >> 5, c2 = idx & 31;
    unsigned pw = packbf(W_hh[rw * 64 + 2 * c2], W_hh[rw * 64 + 2 * c2 + 1]);
    int gr = c2 >> 2;
    whh_l[rw * 32 + ((gr ^ (rw & 7)) << 2) + (c2 & 3)] = pw;
  }
  __syncthreads();

  // gm1[b][g] = emb16[b] . W_ih[g,1:] + b_ih[g] + b_hh[g]
  for (int g = tid; g < 256; g += 128) {
    float acc[8];
    #pragma unroll
    for (int bb = 0; bb < 8; ++bb) acc[bb] = 0.0f;
    const float* wr = &W_ih[g * 65 + 1];
    for (int k = 0; k < 64; ++k) {
      float w = wr[k];
      #pragma unroll
      for (int bb = 0; bb < 8; ++bb) acc[bb] += w * emb16[bb][k];
    }
    float bias = b_ih[g] + b_hh[g];
    int gg = g >> 2;
    #pragma unroll
    for (int bb = 0; bb < 8; ++bb)
      gm1_l[bb * 256 + ((gg ^ bb) << 2) + (g & 3)] = acc[bb] + bias;
  }

  // ---- per-wave weight fragments: jt = 2wv+j, j=0,1 ----
  bf16x8 w0f[2][2], w1f[2][2], w2f[2][2];
  #pragma unroll
  for (int j = 0; j < 2; ++j) {
    const int fm = 16 * (2 * wv + j) + b;   // A row = feature
    #pragma unroll
    for (int kt = 0; kt < 2; ++kt) {
      const float* r0 = &W0[fm * 65 + 1 + kt * 32 + q * 8];
      const float* r1 = &W1[fm * 64 +     kt * 32 + q * 8];
      const float* r2 = &W2[fm * 64 +     kt * 32 + q * 8];
      bf16x8 a, bb, c;
      #pragma unroll
      for (int e = 0; e < 8; ++e) {
        a[e] = (__bf16)r0[e]; bb[e] = (__bf16)r1[e]; c[e] = (__bf16)r2[e];
      }
      w0f[j][kt] = a; w1f[j][kt] = bb; w2f[j][kt] = c;
    }
  }
  f32x4 wiv[2], b0v[2], b1v[2], b2v[2], c0v[2];
  #pragma unroll
  for (int j = 0; j < 2; ++j) {
    const int fb = 16 * (2 * wv + j) + 4 * q;
    #pragma unroll
    for (int r = 0; r < 4; ++r) wiv[j][r] = Wi[fb + r];
    b0v[j] = *(const f32x4*)&b0_l[fb];
    b1v[j] = *(const f32x4*)&b1_l[fb];
    b2v[j] = *(const f32x4*)&b2_l[fb];
    c0v[j] = *(const f32x4*)&w0c0_l[fb];
  }
  const float bi_s = bi[0];
  const f32x4 zf = (f32x4){0.f, 0.f, 0.f, 0.f};
  __syncthreads();

  // helpers ----------------------------------------------------------------
  auto write_x = [&](unsigned* buf, const f32x4* v) {   // v[j], j=0,1
    #pragma unroll
    for (int j = 0; j < 2; ++j) {
      int gr = (2 * (2 * wv + j) + (q >> 1)) ^ xsw;
      int wb = b * 32 + (gr << 2) + ((q & 1) << 1);
      buf[wb]     = packbf(v[j][0], v[j][1]);
      buf[wb + 1] = packbf(v[j][2], v[j][3]);
    }
  };
  auto read_bfrag = [&](const unsigned* buf, int kt) -> bf16x8 {
    int gr = (kt * 4 + q) ^ xsw;
    return *(const bf16x8*)((const char*)buf + b * 128 + gr * 16);
  };
  auto whh_frag = [&](int R, int kt) -> bf16x8 {
    int rw = R * 16 + b;
    int gr = (kt * 4 + q) ^ xsw;
    return *(const bf16x8*)((const char*)whh_l + rw * 128 + gr * 16);
  };
  auto ld_gm1 = [&](int R) -> f32x4 {
    int gr = (R * 4 + q) ^ bm;
    return *(const f32x4*)((const char*)gm1_l + bm * 1024 + gr * 16);
  };
  auto isect_partial = [&](float* pb, const f32x4* v) {
    float part = 0.f;
    #pragma unroll
    for (int j = 0; j < 2; ++j)
      #pragma unroll
      for (int r = 0; r < 4; ++r) part += wiv[j][r] * v[j][r];
    part += __shfl_xor(part, 16);
    part += __shfl_xor(part, 32);
    if (l < 16) pb[b * 2 + wv] = part;   // q==0 lanes publish
  };

  // ---- state ----
  f32x4 hst[2] = {zf, zf}, cst[2] = {zf, zf};
  float nll_acc = 0.f, m_acc = 0.f;
  const float sel0 = (wv == 0 && q == 0 && b < 8) ? 1.0f : 0.0f;

  f32x4 hh[2];
  float integ, dtt, st, tb;

  // one Euler substep; BA/BB compile-time buffer refs, PB the pint buffer
  auto euler_substep = [&](unsigned* BA, unsigned* BB, float* PB) {
    isect_partial(PB, hh);
    write_x(BA, hh);
    __syncthreads();
    bf16x8 Bf0 = read_bfrag(BA, 0), Bf1 = read_bfrag(BA, 1);

    // layer 1 (bias + rank-1 time col as C-in), split-C independent pairs
    f32x4 a0[2], a1[2];
    #pragma unroll
    for (int j = 0; j < 2; ++j) {
      f32x4 cin;
      #pragma unroll
      for (int r = 0; r < 4; ++r) cin[r] = b0v[j][r] + c0v[j][r] * st;
      a0[j] = MFMA16(w0f[j][0], Bf0, cin);
      a1[j] = MFMA16(w0f[j][1], Bf1, zf);
    }
    {   // all waves symmetric: integ from published partials (fills MFMA lat)
      integ += dtt * softplus_fast(PB[b * 2] + PB[b * 2 + 1] + bi_s);
    }
    f32x4 y[2];
    #pragma unroll
    for (int j = 0; j < 2; ++j)
      #pragma unroll
      for (int r = 0; r < 4; ++r) y[j][r] = tanh_fast(a0[j][r] + a1[j][r]);
    write_x(BB, y);
    __syncthreads();
    Bf0 = read_bfrag(BB, 0); Bf1 = read_bfrag(BB, 1);

    // layer 2
    #pragma unroll
    for (int j = 0; j < 2; ++j) {
      a0[j] = MFMA16(w1f[j][0], Bf0, b1v[j]);
      a1[j] = MFMA16(w1f[j][1], Bf1, zf);
    }
    #pragma unroll
    for (int j = 0; j < 2; ++j)
      #pragma unroll
      for (int r = 0; r < 4; ++r) y[j][r] = tanh_fast(a0[j][r] + a1[j][r]);
    write_x(BA, y);
    __syncthreads();
    Bf0 = read_bfrag(BA, 0); Bf1 = read_bfrag(BA, 1);

    // layer 3 + Euler update
    #pragma unroll
    for (int j = 0; j < 2; ++j) {
      a0[j] = MFMA16(w2f[j][0], Bf0, b2v[j]);
      a1[j] = MFMA16(w2f[j][1], Bf1, zf);
    }
    #pragma unroll
    for (int j = 0; j < 2; ++j)
      #pragma unroll
      for (int r = 0; r < 4; ++r) hh[j][r] += dtt * tanh_fast(a0[j][r] + a1[j][r]);
    st += dtt;
  };

  #pragma unroll 1
  for (int step = 0; step < T_LEN; ++step) {
    tb  = tim_l[bm][step];
    dtt = 0.1f * tb;
    hh[0] = hst[0]; hh[1] = hst[1];
    integ = 0.f;
    st  = 0.f;

    #pragma unroll 1
    for (int s2 = 0; s2 < 5; ++s2) {
      euler_substep(xb0, xb1, pint[0]);   // even substep
      euler_substep(xb1, xb0, pint[1]);   // odd substep
    }

    // step end: intensity partials + h_ode exchange (xb2) + store
    isect_partial(pint[2], hh);
    write_x(xb2, hh);
    if (b < 8) {
      size_t obase = 1 + (((size_t)row) * T_LEN + step) * 64 + 4 * q;
      #pragma unroll
      for (int j = 0; j < 2; ++j) {
        size_t o = obase + 16 * (2 * wv + j);
        out[o + 0] = hh[j][0]; out[o + 1] = hh[j][1];
        out[o + 2] = hh[j][2]; out[o + 3] = hh[j][3];
      }
    }
    __syncthreads();
    bf16x8 Bf0 = read_bfrag(xb2, 0), Bf1 = read_bfrag(xb2, 1);

    // LSTM gates: wave wv covers gate rows R = 4g + 2wv + j (its features)
    f32x4 ga[4][2];
    #pragma unroll
    for (int g = 0; g < 4; ++g) {
      #pragma unroll
      for (int j = 0; j < 2; ++j) {
        const int Rb = 4 * g + 2 * wv + j;
        f32x4 gm = ld_gm1(Rb);
        f32x4 wc = *(const f32x4*)&wihc0_l[Rb * 16 + q * 4];
        f32x4 cin;
        #pragma unroll
        for (int r = 0; r < 4; ++r) cin[r] = gm[r] + wc[r] * tb;
        f32x4 a = MFMA16(whh_frag(Rb, 0), Bf0, cin);
        ga[g][j] = MFMA16(whh_frag(Rb, 1), Bf1, a);
      }
    }
    // nll (all waves symmetric; only sel0 lanes accumulate)
    {
      float inten = softplus_fast(pint[2][b * 2] + pint[2][b * 2 + 1] + bi_s);
      float nll = -(log2_f(inten) * kLN2) + integ;
      float mval = msk_l[bm][step];
      nll_acc += sel0 * mval * nll;
      m_acc   += sel0 * mval;
    }
    #pragma unroll
    for (int j = 0; j < 2; ++j)
      #pragma unroll
      for (int r = 0; r < 4; ++r) {
        float ig = sigm_fast(ga[0][j][r]), fg = sigm_fast(ga[1][j][r]);
        float gg = tanh_fast(ga[2][j][r]), og = sigm_fast(ga[3][j][r]);
        float cn = fg * cst[j][r] + ig * gg;
        cst[j][r] = cn;
        hst[j][r] = og * tanh_fast(cn);
      }
  } // time loop

  if (wv == 0) {
    #pragma unroll
    for (int off = 1; off < 64; off <<= 1) {
      nll_acc += __shfl_xor(nll_acc, off);
      m_acc   += __shfl_xor(m_acc, off);
    }
    if (tid == 0) {
      atomicAdd(&ws[0], nll_acc);
      atomicAdd(&ws[1], m_acc);
    }
  }
}

__global__ void jumpode_fin(const float* __restrict__ ws, float* __restrict__ out) {
  if (threadIdx.x == 0 && blockIdx.x == 0) out[0] = ws[0] / ws[1];
}

extern "C" void kernel_launch(void* const* d_in, const int* in_sizes, int n_in,
                              void* d_out, int out_size, void* d_ws, size_t ws_size,
                              hipStream_t stream) {
  (void)in_sizes; (void)n_in; (void)out_size; (void)ws_size;
  const float* times = (const float*)d_in[0];
  const int*   marks = (const int*)  d_in[1];
  const float* maskp = (const float*)d_in[2];
  const float* W0    = (const float*)d_in[3];
  const float* b0    = (const float*)d_in[4];
  const float* W1    = (const float*)d_in[5];
  const float* b1    = (const float*)d_in[6];
  const float* W2    = (const float*)d_in[7];
  const float* b2    = (const float*)d_in[8];
  const float* Wi    = (const float*)d_in[9];
  const float* bi    = (const float*)d_in[10];
  const float* emb   = (const float*)d_in[11];
  const float* W_ih  = (const float*)d_in[12];
  const float* W_hh  = (const float*)d_in[13];
  const float* b_ih  = (const float*)d_in[14];
  const float* b_hh  = (const float*)d_in[15];
  float* out = (float*)d_out;
  float* ws  = (float*)d_ws;

  (void)hipMemsetAsync(d_ws, 0, 2 * sizeof(float), stream);
  jumpode_main<<<dim3(256), dim3(128), 0, stream>>>(
      times, marks, maskp, W0, b0, W1, b1, W2, b2, Wi, bi, emb,
      W_ih, W_hh, b_ih, b_hh, out, ws);
  jumpode_fin<<<dim3(1), dim3(64), 0, stream>>>(ws, out);
}

// Round 9
// 905.990 us; speedup vs baseline: 1.4812x; 1.4812x over previous
//
#include <hip/hip_runtime.h>

// ============================================================================
// JumpODE (B=2048, T=128, H=64, N_STEPS=10) fused persistent kernel, gfx950.
// Round 9: R5 skeleton (256 blocks x 4 waves, 8 real rows, 3 phases/substep,
// 1 block/CU) + in-phase critical-path shaves:
//   (1) no-shfl intensity: lanes publish raw dot4 partials (stride-20,
//       conflict-free); consumer sums 16 via 4x ds_read_b128 in MFMA slack,
//       symmetric across waves.
//   (2) halved exchange: only b<8 lanes write xbuf; readers use (b&7) ->
//       mirrored lanes broadcast-read identical addresses (free on LDS).
//   (3) symmetric nll on all waves (sel0-masked accumulate).
// Structural alternatives all measured worse: 2 blocks/CU (R4 +27%, R6 +42%),
// L1-dup 2-phase (R7), 2-wave barriers (R8 +30%).
//
// Fragment layouts (16x16x32 bf16, learn_hip verified):
//   A: row m = lane&15,  k = (lane>>4)*8 + e
//   B: col n = lane&15,  k = (lane>>4)*8 + e
//   C/D: col n = lane&15, row m = (lane>>4)*4 + reg
// ============================================================================

#define T_LEN 128

typedef float  f32x4  __attribute__((ext_vector_type(4)));
typedef __bf16 bf16x8 __attribute__((ext_vector_type(8)));
typedef __bf16 bf16x2 __attribute__((ext_vector_type(2)));

#define MFMA16(a, b, c) __builtin_amdgcn_mfma_f32_16x16x32_bf16((a), (b), (c), 0, 0, 0)

__device__ __forceinline__ float rcp_f(float x) { return __builtin_amdgcn_rcpf(x); }
__device__ __forceinline__ float exp2_f(float x) { return __builtin_amdgcn_exp2f(x); }
__device__ __forceinline__ float log2_f(float x) { return __builtin_amdgcn_logf(x); }

constexpr float kL2E = 1.44269504088896340736f;
constexpr float kLN2 = 0.69314718055994530942f;

__device__ __forceinline__ float tanh_fast(float x) {
  float e = exp2_f(x * (2.0f * kL2E));
  return 1.0f - 2.0f * rcp_f(e + 1.0f);
}
__device__ __forceinline__ float sigm_fast(float x) {
  return rcp_f(1.0f + exp2_f(-kL2E * x));
}
__device__ __forceinline__ float softplus_fast(float x) {
  float neg = log2_f(1.0f + exp2_f(-kL2E * fabsf(x))) * kLN2;
  return fmaxf(x, 0.0f) + neg;
}
__device__ __forceinline__ unsigned packbf(float a, float b) {
  bf16x2 v; v[0] = (__bf16)a; v[1] = (__bf16)b;   // RNE
  return __builtin_bit_cast(unsigned, v);
}

__launch_bounds__(256)
__global__ void jumpode_main(
    const float* __restrict__ times, const int* __restrict__ marks,
    const float* __restrict__ maskp, const float* __restrict__ W0,
    const float* __restrict__ b0,    const float* __restrict__ W1,
    const float* __restrict__ b1,    const float* __restrict__ W2,
    const float* __restrict__ b2,    const float* __restrict__ Wi,
    const float* __restrict__ bi,    const float* __restrict__ emb,
    const float* __restrict__ W_ih,  const float* __restrict__ W_hh,
    const float* __restrict__ b_ih,  const float* __restrict__ b_hh,
    float* __restrict__ out, float* __restrict__ ws)
{
  // ---- LDS (~58 KB, 1 block/CU) ----
  __shared__ __align__(16) unsigned whh_l[256 * 32];   // bf16 pairs, swizzled, 32 KB
  __shared__ __align__(16) float    gm1_l[8 * 256];    // m1@Wih^T + biases, swizzled, 8 KB
  __shared__ __align__(16) unsigned xb0[16 * 32];      // activation X^T bf16 buffers
  __shared__ __align__(16) unsigned xb1[16 * 32];
  __shared__ __align__(16) unsigned xb2[16 * 32];      // step-end / LSTM input
  __shared__ __align__(16) float    pint[3][160];      // raw dot4 partials, stride 20
  __shared__ __align__(16) float    b0_l[64], b1_l[64], b2_l[64];
  __shared__ __align__(16) float    w0c0_l[64];        // W0[:,0]
  __shared__ __align__(16) float    wihc0_l[256];      // W_ih[:,0]
  __shared__ __align__(16) float    emb16[8][64];
  __shared__ __align__(16) float    tim_l[8][T_LEN];
  __shared__ __align__(16) float    msk_l[8][T_LEN];

  const int tid = threadIdx.x;          // 0..255
  const int wv  = tid >> 6;             // wave id = feature block jt
  const int l   = tid & 63;
  const int b   = l & 15;               // MFMA batch column
  const int q   = l >> 4;               // lane quad
  const int bm  = b & 7;                // real batch row within block
  const int row = blockIdx.x * 8 + bm;  // global batch row
  const int xsw = bm;                   // xor-swizzle key (= b&7)

  // ---- staging (256 threads) ----
  if (tid < 64) {
    b0_l[tid] = b0[tid]; b1_l[tid] = b1[tid]; b2_l[tid] = b2[tid];
    w0c0_l[tid] = W0[tid * 65];
  }
  wihc0_l[tid] = W_ih[tid * 65];
  for (int idx = tid; idx < 512; idx += 256) {
    int rr = idx >> 6, cc = idx & 63;
    int mk = marks[(blockIdx.x * 8 + rr) * T_LEN + 1];
    emb16[rr][cc] = emb[mk * 64 + cc];
  }
  for (int idx = tid; idx < 1024; idx += 256) {
    int rr = idx >> 7, cc = idx & 127;
    tim_l[rr][cc] = times[(blockIdx.x * 8 + rr) * T_LEN + cc];
    msk_l[rr][cc] = maskp[(blockIdx.x * 8 + rr) * T_LEN + cc];
  }
  #pragma unroll 4
  for (int i = 0; i < 32; ++i) {                      // W_hh -> bf16 swizzled
    int idx = i * 256 + tid;                          // word: row*32 + c2
    int rw = idx >> 5, c2 = idx & 31;
    unsigned pw = packbf(W_hh[rw * 64 + 2 * c2], W_hh[rw * 64 + 2 * c2 + 1]);
    int gr = c2 >> 2;
    whh_l[rw * 32 + ((gr ^ (rw & 7)) << 2) + (c2 & 3)] = pw;
  }
  __syncthreads();

  // gm1[b][g] = emb16[b] . W_ih[g,1:] + b_ih[g] + b_hh[g]
  {
    int g = tid;
    float acc[8];
    #pragma unroll
    for (int bb = 0; bb < 8; ++bb) acc[bb] = 0.0f;
    const float* wr = &W_ih[g * 65 + 1];
    for (int k = 0; k < 64; ++k) {
      float w = wr[k];
      #pragma unroll
      for (int bb = 0; bb < 8; ++bb) acc[bb] += w * emb16[bb][k];
    }
    float bias = b_ih[g] + b_hh[g];
    int gg = g >> 2;
    #pragma unroll
    for (int bb = 0; bb < 8; ++bb)
      gm1_l[bb * 256 + ((gg ^ bb) << 2) + (g & 3)] = acc[bb] + bias;
  }

  // ---- per-wave weight fragments (features 16wv..16wv+15) ----
  bf16x8 w0f[2], w1f[2], w2f[2];
  {
    const int fm = 16 * wv + b;         // A row = feature
    #pragma unroll
    for (int kt = 0; kt < 2; ++kt) {
      const float* r0 = &W0[fm * 65 + 1 + kt * 32 + q * 8];
      const float* r1 = &W1[fm * 64 +     kt * 32 + q * 8];
      const float* r2 = &W2[fm * 64 +     kt * 32 + q * 8];
      bf16x8 a, bb, c;
      #pragma unroll
      for (int e = 0; e < 8; ++e) {
        a[e] = (__bf16)r0[e]; bb[e] = (__bf16)r1[e]; c[e] = (__bf16)r2[e];
      }
      w0f[kt] = a; w1f[kt] = bb; w2f[kt] = c;
    }
  }
  f32x4 wiv;
  #pragma unroll
  for (int r = 0; r < 4; ++r) wiv[r] = Wi[16 * wv + 4 * q + r];
  const float bi_s = bi[0];
  const f32x4 b0v = *(const f32x4*)&b0_l[16 * wv + 4 * q];
  const f32x4 b1v = *(const f32x4*)&b1_l[16 * wv + 4 * q];
  const f32x4 b2v = *(const f32x4*)&b2_l[16 * wv + 4 * q];
  const f32x4 c0v = *(const f32x4*)&w0c0_l[16 * wv + 4 * q];
  const f32x4 zf  = (f32x4){0.f, 0.f, 0.f, 0.f};
  __syncthreads();

  // helpers ----------------------------------------------------------------
  auto write_x = [&](unsigned* buf, const f32x4 v) {   // only real cols write
    if (b < 8) {
      int gr = (2 * wv + (q >> 1)) ^ xsw;
      int wb = b * 32 + (gr << 2) + ((q & 1) << 1);
      buf[wb]     = packbf(v[0], v[1]);
      buf[wb + 1] = packbf(v[2], v[3]);
    }
  };
  auto read_bfrag = [&](const unsigned* buf, int kt) -> bf16x8 {
    int gr = (kt * 4 + q) ^ xsw;       // mirrored lanes broadcast (same addr)
    return *(const bf16x8*)((const char*)buf + bm * 128 + gr * 16);
  };
  auto whh_frag = [&](int R, int kt) -> bf16x8 {
    int rw = R * 16 + b;               // b = feature row here (A-fragment)
    int gr = (kt * 4 + q) ^ (b & 7);
    return *(const bf16x8*)((const char*)whh_l + rw * 128 + gr * 16);
  };
  auto ld_gm1 = [&](int R) -> f32x4 {
    int gr = (R * 4 + q) ^ bm;
    return *(const f32x4*)((const char*)gm1_l + bm * 1024 + gr * 16);
  };
  // publish raw dot4 partial (no shfl): pint[pp][b*20 + wv*4 + q]
  auto isect_partial = [&](float* pb, const f32x4 v) {
    float part = wiv[0] * v[0] + wiv[1] * v[1] + wiv[2] * v[2] + wiv[3] * v[3];
    if (b < 8) pb[b * 20 + wv * 4 + q] = part;
  };
  // consumer: sum 16 partials for this lane's batch col (in MFMA slack)
  auto isect_sum = [&](const float* pb) -> float {
    const char* base = (const char*)pb + bm * 80;
    f32x4 p0 = *(const f32x4*)(base);
    f32x4 p1 = *(const f32x4*)(base + 16);
    f32x4 p2 = *(const f32x4*)(base + 32);
    f32x4 p3 = *(const f32x4*)(base + 48);
    f32x4 s = p0 + p1 + p2 + p3;
    return s[0] + s[1] + s[2] + s[3];
  };

  // ---- state ----
  f32x4 hst = zf, cst = zf;
  float nll_acc = 0.f, m_acc = 0.f;
  const float sel0 = (wv == 0 && q == 0 && b < 8) ? 1.0f : 0.0f;

  f32x4 hh;
  float integ, dtt, st, tb;

  // one Euler substep; BA/BB compile-time buffer refs, PB the pint buffer
  auto euler_substep = [&](unsigned* BA, unsigned* BB, float* PB) {
    isect_partial(PB, hh);
    write_x(BA, hh);
    __syncthreads();
    bf16x8 Bf0 = read_bfrag(BA, 0), Bf1 = read_bfrag(BA, 1);

    // layer 1 (bias + rank-1 time column folded into C-in); split-C pair
    f32x4 cin;
    #pragma unroll
    for (int r = 0; r < 4; ++r) cin[r] = b0v[r] + c0v[r] * st;
    f32x4 a0 = MFMA16(w0f[0], Bf0, cin);
    f32x4 a1 = MFMA16(w0f[1], Bf1, zf);
    // symmetric: every wave folds the intensity term in MFMA latency slack
    integ += dtt * softplus_fast(isect_sum(PB) + bi_s);
    f32x4 y;
    #pragma unroll
    for (int r = 0; r < 4; ++r) y[r] = tanh_fast(a0[r] + a1[r]);
    write_x(BB, y);
    __syncthreads();
    Bf0 = read_bfrag(BB, 0); Bf1 = read_bfrag(BB, 1);

    // layer 2
    a0 = MFMA16(w1f[0], Bf0, b1v);
    a1 = MFMA16(w1f[1], Bf1, zf);
    #pragma unroll
    for (int r = 0; r < 4; ++r) y[r] = tanh_fast(a0[r] + a1[r]);
    write_x(BA, y);
    __syncthreads();
    Bf0 = read_bfrag(BA, 0); Bf1 = read_bfrag(BA, 1);

    // layer 3 + Euler update
    a0 = MFMA16(w2f[0], Bf0, b2v);
    a1 = MFMA16(w2f[1], Bf1, zf);
    #pragma unroll
    for (int r = 0; r < 4; ++r) hh[r] += dtt * tanh_fast(a0[r] + a1[r]);
    st += dtt;
  };

  #pragma unroll 1
  for (int step = 0; step < T_LEN; ++step) {
    tb  = tim_l[bm][step];
    dtt = 0.1f * tb;
    hh  = hst;
    integ = 0.f;
    st  = 0.f;

    #pragma unroll 1
    for (int s2 = 0; s2 < 5; ++s2) {
      euler_substep(xb0, xb1, pint[0]);   // even substep
      euler_substep(xb1, xb0, pint[1]);   // odd substep
    }

    // step end: intensity partials + h_ode exchange (xb2) + store
    isect_partial(pint[2], hh);
    write_x(xb2, hh);
    if (b < 8) {
      size_t obase = 1 + (((size_t)row) * T_LEN + step) * 64 + 16 * wv + 4 * q;
      out[obase + 0] = hh[0]; out[obase + 1] = hh[1];
      out[obase + 2] = hh[2]; out[obase + 3] = hh[3];
    }
    __syncthreads();
    bf16x8 Bf0 = read_bfrag(xb2, 0), Bf1 = read_bfrag(xb2, 1);

    // LSTM gates: wave wv computes gate rows {4g+wv : g=0..3}
    f32x4 ga[4];
    #pragma unroll
    for (int g = 0; g < 4; ++g) {
      const int Rb = 4 * g + wv;
      f32x4 gm = ld_gm1(Rb);
      f32x4 wc = *(const f32x4*)&wihc0_l[Rb * 16 + q * 4];
      f32x4 cin;
      #pragma unroll
      for (int r = 0; r < 4; ++r) cin[r] = gm[r] + wc[r] * tb;
      f32x4 a = MFMA16(whh_frag(Rb, 0), Bf0, cin);
      ga[g] = MFMA16(whh_frag(Rb, 1), Bf1, a);
    }
    {   // symmetric nll (overlaps gate-MFMA latency); sel0-masked accumulate
      float inten = softplus_fast(isect_sum(pint[2]) + bi_s);
      float nll = -(log2_f(inten) * kLN2) + integ;
      float mval = msk_l[bm][step];
      nll_acc += sel0 * mval * nll;
      m_acc   += sel0 * mval;
    }
    #pragma unroll
    for (int r = 0; r < 4; ++r) {
      float ig = sigm_fast(ga[0][r]), fg = sigm_fast(ga[1][r]);
      float gg = tanh_fast(ga[2][r]), og = sigm_fast(ga[3][r]);
      float cn = fg * cst[r] + ig * gg;
      cst[r] = cn;
      hst[r] = og * tanh_fast(cn);
    }
  } // time loop

  if (wv == 0) {
    #pragma unroll
    for (int off = 1; off < 64; off <<= 1) {
      nll_acc += __shfl_xor(nll_acc, off);
      m_acc   += __shfl_xor(m_acc, off);
    }
    if (tid == 0) {
      atomicAdd(&ws[0], nll_acc);
      atomicAdd(&ws[1], m_acc);
    }
  }
}

__global__ void jumpode_fin(const float* __restrict__ ws, float* __restrict__ out) {
  if (threadIdx.x == 0 && blockIdx.x == 0) out[0] = ws[0] / ws[1];
}

extern "C" void kernel_launch(void* const* d_in, const int* in_sizes, int n_in,
                              void* d_out, int out_size, void* d_ws, size_t ws_size,
                              hipStream_t stream) {
  (void)in_sizes; (void)n_in; (void)out_size; (void)ws_size;
  const float* times = (const float*)d_in[0];
  const int*   marks = (const int*)  d_in[1];
  const float* maskp = (const float*)d_in[2];
  const float* W0    = (const float*)d_in[3];
  const float* b0    = (const float*)d_in[4];
  const float* W1    = (const float*)d_in[5];
  const float* b1    = (const float*)d_in[6];
  const float* W2    = (const float*)d_in[7];
  const float* b2    = (const float*)d_in[8];
  const float* Wi    = (const float*)d_in[9];
  const float* bi    = (const float*)d_in[10];
  const float* emb   = (const float*)d_in[11];
  const float* W_ih  = (const float*)d_in[12];
  const float* W_hh  = (const float*)d_in[13];
  const float* b_ih  = (const float*)d_in[14];
  const float* b_hh  = (const float*)d_in[15];
  float* out = (float*)d_out;
  float* ws  = (float*)d_ws;

  (void)hipMemsetAsync(d_ws, 0, 2 * sizeof(float), stream);
  jumpode_main<<<dim3(256), dim3(256), 0, stream>>>(
      times, marks, maskp, W0, b0, W1, b1, W2, b2, Wi, bi, emb,
      W_ih, W_hh, b_ih, b_hh, out, ws);
  jumpode_fin<<<dim3(1), dim3(64), 0, stream>>>(ws, out);
}